// Round 9
// baseline (269.058 us; speedup 1.0000x reference)
//
#include <hip/hip_runtime.h>
#include <math.h>

typedef __attribute__((ext_vector_type(8))) short bf16x8;
typedef __attribute__((ext_vector_type(4))) float f32x4;
typedef __attribute__((ext_vector_type(8))) unsigned short u16x8;

#define BSZ 8
#define SEQ 2048
#define DIM 512
#define BS_TOT (BSZ*SEQ)
#define NX4 (BS_TOT * DIM / 4)
#define NW4 (DIM * DIM / 4)

__device__ __forceinline__ unsigned short f2bf(float f) {
    unsigned int u = __float_as_uint(f);
    unsigned int r = (u + 0x7fffu + ((u >> 16) & 1u)) >> 16;
    return (unsigned short)r;
}

__device__ __forceinline__ f32x4 mfma16(bf16x8 a, bf16x8 b, f32x4 c) {
    return __builtin_amdgcn_mfma_f32_16x16x32_bf16(a, b, c, 0, 0, 0);
}

// Stage a [R rows x 64 cols] bf16 tile into LDS via async global_load_lds (16B/lane).
// XOR-swizzle: LDS slot c holds global chunk c ^ (row&7). R multiple of 32.
#define STAGE64(gbase, rstride, ldsbase, R)                                        \
    {                                                                              \
        _Pragma("unroll")                                                          \
        for (int t_ = 0; t_ < (R) / 32; ++t_) {                                    \
            int r8_ = wave * ((R) / 32) + t_;                                      \
            int row_ = r8_ * 8 + (lane >> 3);                                      \
            int kch_ = (lane & 7) ^ (row_ & 7);                                    \
            const unsigned short* gp_ = (gbase) + (size_t)row_ * (rstride) + kch_ * 8; \
            __builtin_amdgcn_global_load_lds(                                      \
                (const __attribute__((address_space(1))) unsigned int*)gp_,        \
                (__attribute__((address_space(3))) unsigned int*)((ldsbase) + r8_ * 512), \
                16, 0, 0);                                                         \
        }                                                                          \
    }

__device__ __forceinline__ bf16x8 frag_ld(const unsigned short* lds, int row, int kc) {
    return *(const bf16x8*)(lds + row * 64 + (((kc) ^ (row & 7)) << 3));
}

// ---------------- fused fp32 -> bf16 conversion (x, Wq, Wk, Wv in one grid) ----------------
__global__ __launch_bounds__(256) void conv_all(
    const float* __restrict__ x, const float* __restrict__ wq,
    const float* __restrict__ wk, const float* __restrict__ wv,
    unsigned short* __restrict__ xb, unsigned short* __restrict__ wqb,
    unsigned short* __restrict__ wkb, unsigned short* __restrict__ wvb) {
    int i = blockIdx.x * 256 + threadIdx.x;
    const float* s; unsigned short* d; int j;
    if (i < NX4)                { s = x;  d = xb;  j = i; }
    else if (i < NX4 + NW4)     { s = wq; d = wqb; j = i - NX4; }
    else if (i < NX4 + 2 * NW4) { s = wk; d = wkb; j = i - NX4 - NW4; }
    else                        { s = wv; d = wvb; j = i - NX4 - 2 * NW4; }
    float4 v = ((const float4*)s)[j];
    ushort4 o;
    o.x = f2bf(v.x); o.y = f2bf(v.y); o.z = f2bf(v.z); o.w = f2bf(v.w);
    ((ushort4*)d)[j] = o;
}

// ---------------- per-point attr table: 3D unit vector + log2-scaled time ----------------
// {x, y, z, t*log2e}; masked points get t-sentinel 1e9 -> score ~ -1.4e9 -> exp2 -> 0.
__global__ __launch_bounds__(256) void trig_prep(const float* __restrict__ lat,
                                                 const float* __restrict__ lon,
                                                 const float* __restrict__ tm,
                                                 const int* __restrict__ mask,
                                                 float* __restrict__ trigp) {
    int i = blockIdx.x * blockDim.x + threadIdx.x;
    if (i < BS_TOT) {
        const float RAD = 0.017453292519943295f;
        const float LOG2E = 1.442695041f;
        float la = lat[i] * RAD, lo = lon[i] * RAD;
        float cla = cosf(la);
        float4 o = {cla * cosf(lo), cla * sinf(lo), sinf(la),
                    mask[i] ? tm[i] * LOG2E : 1e9f};
        ((float4*)trigp)[i] = o;
    }
}

// ---------------- QKV projection GEMM: one 128x128 tile of one output ----------------
// grid (BS_TOT/128, 12): y -> (o = y>>2, n0 = (y&3)*128)
// o==2 (V): epilogue transposes the tile through LDS so the V^T store is
// 16B/lane, 256B-contiguous per 16 lanes. LDS reused: Ts aliases As|Bs.
// launch_bounds (256,4): 4 blocks/CU co-resident to hide barrier drains.
__global__ __launch_bounds__(256, 4) void qkv_gemm(
    const unsigned short* __restrict__ xb,
    const unsigned short* __restrict__ Wqb, const unsigned short* __restrict__ Wkb,
    const unsigned short* __restrict__ Wvb,
    const float* __restrict__ bq, const float* __restrict__ bk, const float* __restrict__ bv,
    unsigned short* __restrict__ Qb, unsigned short* __restrict__ Kb,
    unsigned short* __restrict__ VTb) {
    __shared__ __align__(16) unsigned short smem[128 * 128];   // 32 KB
    unsigned short* const As = smem;               // [128*64]
    unsigned short* const Bs = smem + 128 * 64;    // [128*64]

    const int tid = threadIdx.x, lane = tid & 63, wave = tid >> 6;
    const int lq = lane & 15, quad = lane >> 4;
    const int w0 = wave & 1, w1 = wave >> 1;
    const int m0 = blockIdx.x * 128;
    const int o = blockIdx.y >> 2, n0 = (blockIdx.y & 3) * 128;
    const unsigned short* W = (o == 0) ? Wqb : (o == 1) ? Wkb : Wvb;
    const float* bias = (o == 0) ? bq : (o == 1) ? bk : bv;

    f32x4 acc[4][4];
    #pragma unroll
    for (int mi = 0; mi < 4; ++mi)
        #pragma unroll
        for (int ni = 0; ni < 4; ++ni) acc[mi][ni] = (f32x4){0.f, 0.f, 0.f, 0.f};

    const unsigned short* Ag = xb + (size_t)m0 * DIM;
    const unsigned short* Bg = W + (size_t)n0 * DIM;

    for (int kc = 0; kc < 8; ++kc) {
        __syncthreads();
        STAGE64(Ag + kc * 64, DIM, As, 128);
        STAGE64(Bg + kc * 64, DIM, Bs, 128);
        __syncthreads();
        #pragma unroll
        for (int ks = 0; ks < 2; ++ks) {
            bf16x8 af[4], bfr[4];
            #pragma unroll
            for (int mi = 0; mi < 4; ++mi) af[mi] = frag_ld(As, w0 * 64 + mi * 16 + lq, ks * 4 + quad);
            #pragma unroll
            for (int ni = 0; ni < 4; ++ni) bfr[ni] = frag_ld(Bs, w1 * 64 + ni * 16 + lq, ks * 4 + quad);
            #pragma unroll
            for (int mi = 0; mi < 4; ++mi)
                #pragma unroll
                for (int ni = 0; ni < 4; ++ni)
                    acc[mi][ni] = mfma16(af[mi], bfr[ni], acc[mi][ni]);
        }
    }

    if (o < 2) {
        unsigned short* G = (o == 0) ? Qb : Kb;
        #pragma unroll
        for (int ni = 0; ni < 4; ++ni) {
            int e = n0 + w1 * 64 + ni * 16 + lq;
            float be = bias[e];
            #pragma unroll
            for (int mi = 0; mi < 4; ++mi)
                #pragma unroll
                for (int r = 0; r < 4; ++r) {
                    int mrow = m0 + w0 * 64 + mi * 16 + quad * 4 + r;
                    G[(size_t)mrow * DIM + e] = f2bf(acc[mi][ni][r] + be);
                }
        }
    } else {
        // ---- V: transpose through LDS, coalesced V^T store ----
        __syncthreads();   // all waves done reading As/Bs
        #pragma unroll
        for (int ni = 0; ni < 4; ++ni) {
            int e = w1 * 64 + ni * 16 + lq;
            float be = bias[n0 + e];
            #pragma unroll
            for (int mi = 0; mi < 4; ++mi) {
                int s = w0 * 64 + mi * 16 + quad * 4;
                ushort4 pk;
                pk.x = f2bf(acc[mi][ni][0] + be);
                pk.y = f2bf(acc[mi][ni][1] + be);
                pk.z = f2bf(acc[mi][ni][2] + be);
                pk.w = f2bf(acc[mi][ni][3] + be);
                int addr = (e * 256 + s * 2) ^ ((e & 7) << 4);
                *(ushort4*)((char*)smem + addr) = pk;
            }
        }
        __syncthreads();
        const int bb = m0 >> 11, sbase = m0 & 2047;
        #pragma unroll
        for (int p = 0; p < 8; ++p) {
            int e = p * 16 + (tid >> 4);
            int s0 = (tid & 15) * 8;
            int addr = (e * 256 + s0 * 2) ^ ((e & 7) << 4);
            u16x8 v = *(const u16x8*)((const char*)smem + addr);
            *(u16x8*)&VTb[((size_t)bb * DIM + n0 + e) * SEQ + sbase + s0] = v;
        }
    }
}

// ---------------- phase 1: 128x128 score tile, NO-SHIFT softmax + distance screen ----------------
// log2-domain scores: s2 = qk*scale*log2e - 2R*log2e*asin(u) - |dt|*log2e.
// SCREEN (exactness-preserving): asin(u) >= u, so
//   s2 <= qkS - HQ*sqrt(ch2) - dt   (HQ = R*log2e, u = sqrt(ch2)/2).
// Skip iff ch2 > t^2 with t = (qkS - dt + 160)/HQ  =>  true s2 < -160 < -149
// => exp2 underflows to exactly 0.0f => store 0, skip sum: BIT-IDENTICAL.
// With uniform-random geo data ~97% of 16x16 subtiles screen fully (wave-
// coherent via __any) -> skips asin poly, 2 sqrt, exp2 on the fast path.
// Masked keys (dt~1.4e9 -> t<0 -> t^2 huge) never screen -> correct slow path.
// grid: 1D 2048, b = id&7 -> one batch per XCD.
__global__ __launch_bounds__(256, 3) void score_kernel(
    const unsigned short* __restrict__ Qb, const unsigned short* __restrict__ Kb,
    const float* __restrict__ trigp, unsigned short* __restrict__ Pbuf,
    float* __restrict__ Lc) {
    __shared__ __align__(16) unsigned short As[128 * 64];
    __shared__ __align__(16) unsigned short Bs[128 * 64];

    const int tid = threadIdx.x, lane = tid & 63, wave = tid >> 6;
    const int lq = lane & 15, quad = lane >> 4;
    const int w0 = wave & 1, w1 = wave >> 1;
    const int id = blockIdx.x;
    const int b = id & 7, t = id >> 3;
    const int it = t & 15, jt = t >> 4;
    const int i0 = it * 128, j0 = jt * 128;
    const size_t rowQ = (size_t)b * SEQ + i0;
    const size_t rowK = (size_t)b * SEQ + j0;

    f32x4 acc[4][4];
    #pragma unroll
    for (int mi = 0; mi < 4; ++mi)
        #pragma unroll
        for (int ni = 0; ni < 4; ++ni) acc[mi][ni] = (f32x4){0.f, 0.f, 0.f, 0.f};

    const unsigned short* Ag = Qb + rowQ * DIM;
    const unsigned short* Bg = Kb + rowK * DIM;

    for (int kc = 0; kc < 8; ++kc) {
        __syncthreads();
        STAGE64(Ag + kc * 64, DIM, As, 128);
        STAGE64(Bg + kc * 64, DIM, Bs, 128);
        __syncthreads();
        #pragma unroll
        for (int ks = 0; ks < 2; ++ks) {
            bf16x8 af[4], bfr[4];
            #pragma unroll
            for (int mi = 0; mi < 4; ++mi) af[mi] = frag_ld(As, w0 * 64 + mi * 16 + lq, ks * 4 + quad);
            #pragma unroll
            for (int ni = 0; ni < 4; ++ni) bfr[ni] = frag_ld(Bs, w1 * 64 + ni * 16 + lq, ks * 4 + quad);
            #pragma unroll
            for (int mi = 0; mi < 4; ++mi)
                #pragma unroll
                for (int ni = 0; ni < 4; ++ni)
                    acc[mi][ni] = mfma16(af[mi], bfr[ni], acc[mi][ni]);
        }
    }

    // ---- constants (all folded with log2e) ----
    const float SC2 = 0.04419417382415922f * 1.442695041f;   // (1/sqrt(512))*log2e
    const float KQ = 12742.0f * 1.442695041f;                // 2R*log2e
    const float KHPI = 12742.0f * 1.442695041f * 1.5707963268f;
    const float INVHQ = 1.0f / (6371.0f * 1.442695041f);     // 1/(R*log2e)
    const float C160 = 160.0f * INVHQ;
    // A&S 4.4.47: asin(u) = pi/2 - sqrt(1-u)*P(u), |eps| <= 2e-8
    const float A0 = 1.5707963050f, A1 = -0.2145988016f, A2 = 0.0889789874f,
                A3 = -0.0501743046f, A4 = 0.0308918810f, A5 = -0.0170881256f,
                A6 = 0.0066700901f, A7 = -0.0012624911f;

    // ---- fused sweep: screen -> (bias -> exp2) -> partial row sum -> store P ----
    float sm[16];
    #pragma unroll
    for (int i = 0; i < 16; ++i) sm[i] = 0.f;

    // hoist the 4 K-attr loads (reused across all mi)
    float4 ka[4];
    #pragma unroll
    for (int ni = 0; ni < 4; ++ni)
        ka[ni] = ((const float4*)trigp)[rowK + w1 * 64 + ni * 16 + lq];

    #pragma unroll
    for (int mi = 0; mi < 4; ++mi) {
        float4 qa[4];
        #pragma unroll
        for (int r = 0; r < 4; ++r)
            qa[r] = ((const float4*)trigp)[rowQ + w0 * 64 + mi * 16 + quad * 4 + r];
        #pragma unroll
        for (int ni = 0; ni < 4; ++ni) {
            float4 k = ka[ni];
            float c2[4], dtv[4], qkS[4];
            int need = 0;
            #pragma unroll
            for (int r = 0; r < 4; ++r) {
                float dx = qa[r].x - k.x;
                float dy = qa[r].y - k.y;
                float dz = qa[r].z - k.z;
                c2[r] = fmaf(dx, dx, fmaf(dy, dy, dz * dz));   // chord^2
                qkS[r] = acc[mi][ni][r] * SC2;
                dtv[r] = fabsf(k.w - qa[r].w);
                float tt = fmaf(qkS[r] - dtv[r], INVHQ, C160);
                need |= (c2[r] <= tt * tt) ? 1 : 0;
            }
            if (__any(need)) {
                #pragma unroll
                for (int r = 0; r < 4; ++r) {
                    float u = fminf(0.5f * __builtin_amdgcn_sqrtf(c2[r]), 1.0f);
                    float vv = __builtin_amdgcn_sqrtf(1.0f - u);
                    float pl = fmaf(A7, u, A6);
                    pl = fmaf(pl, u, A5); pl = fmaf(pl, u, A4); pl = fmaf(pl, u, A3);
                    pl = fmaf(pl, u, A2); pl = fmaf(pl, u, A1); pl = fmaf(pl, u, A0);
                    float sv = fmaf(vv * pl, KQ, qkS[r] - KHPI) - dtv[r];
                    float p = __builtin_amdgcn_exp2f(sv);
                    sm[mi * 4 + r] += p;
                    Pbuf[(rowQ + w0 * 64 + mi * 16 + quad * 4 + r) * SEQ + j0 +
                         w1 * 64 + ni * 16 + lq] = f2bf(p);
                }
            } else {
                #pragma unroll
                for (int r = 0; r < 4; ++r)
                    Pbuf[(rowQ + w0 * 64 + mi * 16 + quad * 4 + r) * SEQ + j0 +
                         w1 * 64 + ni * 16 + lq] = 0;
            }
        }
    }
    #pragma unroll
    for (int o = 1; o < 16; o <<= 1)
        #pragma unroll
        for (int i = 0; i < 16; ++i) sm[i] += __shfl_xor(sm[i], o);

    if (lq == 0) {
        int chunk = jt * 2 + w1;
        #pragma unroll
        for (int mi = 0; mi < 4; ++mi)
            #pragma unroll
            for (int r = 0; r < 4; ++r) {
                size_t g = rowQ + w0 * 64 + mi * 16 + quad * 4 + r;
                Lc[g * 32 + chunk] = sm[mi * 4 + r];
            }
    }
}

// ---------------- phase 1.5: per-row 1/L ----------------
__global__ __launch_bounds__(256) void rowinv(
    const float* __restrict__ Lc, float* __restrict__ Srow) {
    int g = blockIdx.x * 256 + threadIdx.x;
    if (g >= BS_TOT) return;
    float L = 0.f;
    #pragma unroll
    for (int c = 0; c < 32; ++c) L += Lc[(size_t)g * 32 + c];
    Srow[g] = 1.0f / L;
}

// ---------------- phase 2: O = Srow * (P V) — pure GEMM, scale in epilogue ----------------
// 128x64 tile (proven config): 1024 blocks = 4 blocks/CU full co-residency.
// grid: 1D 1024, b = id&7 -> batch-per-XCD (VT slab = 2MB stays L2-resident).
__global__ __launch_bounds__(256, 4) void pv_kernel(
    const unsigned short* __restrict__ Pbuf, const unsigned short* __restrict__ VTb,
    const float* __restrict__ Srow, float* __restrict__ Out) {
    __shared__ __align__(16) unsigned short As[128 * 64];
    __shared__ __align__(16) unsigned short Bs[64 * 64];

    const int tid = threadIdx.x, lane = tid & 63, wave = tid >> 6;
    const int lq = lane & 15, quad = lane >> 4;
    const int id = blockIdx.x;
    const int b = id & 7, t = id >> 3;
    const int d0 = (t & 7) * 64, i0 = (t >> 3) * 128;

    f32x4 acc[2][4];
    #pragma unroll
    for (int mi = 0; mi < 2; ++mi)
        #pragma unroll
        for (int ni = 0; ni < 4; ++ni) acc[mi][ni] = (f32x4){0.f, 0.f, 0.f, 0.f};

    const unsigned short* Ag = Pbuf + ((size_t)b * SEQ + i0) * SEQ;
    const unsigned short* Bg = VTb + ((size_t)b * DIM + d0) * SEQ;

    #pragma unroll 1
    for (int kc = 0; kc < 32; ++kc) {
        __syncthreads();
        STAGE64(Ag + kc * 64, SEQ, As, 128);
        STAGE64(Bg + kc * 64, SEQ, Bs, 64);
        __syncthreads();
        #pragma unroll
        for (int ks = 0; ks < 2; ++ks) {
            bf16x8 af[2], bfr[4];
            #pragma unroll
            for (int mi = 0; mi < 2; ++mi) af[mi] = frag_ld(As, wave * 32 + mi * 16 + lq, ks * 4 + quad);
            #pragma unroll
            for (int ni = 0; ni < 4; ++ni) bfr[ni] = frag_ld(Bs, ni * 16 + lq, ks * 4 + quad);
            #pragma unroll
            for (int mi = 0; mi < 2; ++mi)
                #pragma unroll
                for (int ni = 0; ni < 4; ++ni)
                    acc[mi][ni] = mfma16(af[mi], bfr[ni], acc[mi][ni]);
        }
    }

    #pragma unroll
    for (int mi = 0; mi < 2; ++mi)
        #pragma unroll
        for (int r = 0; r < 4; ++r) {
            size_t grow = (size_t)b * SEQ + i0 + wave * 32 + mi * 16 + quad * 4 + r;
            float s = Srow[grow];
            size_t orow = grow * DIM;
            #pragma unroll
            for (int ni = 0; ni < 4; ++ni)
                Out[orow + d0 + ni * 16 + lq] = acc[mi][ni][r] * s;
        }
}

extern "C" void kernel_launch(void* const* d_in, const int* in_sizes, int n_in,
                              void* d_out, int out_size, void* d_ws, size_t ws_size,
                              hipStream_t stream) {
    (void)in_sizes; (void)n_in; (void)out_size; (void)ws_size;
    const float* x    = (const float*)d_in[0];
    const float* tseq = (const float*)d_in[1];
    const float* lat  = (const float*)d_in[2];
    const float* lon  = (const float*)d_in[3];
    const int*   mk   = (const int*)d_in[4];
    const float* Wq   = (const float*)d_in[5];
    const float* bq   = (const float*)d_in[6];
    const float* Wk   = (const float*)d_in[7];
    const float* bk   = (const float*)d_in[8];
    const float* Wv   = (const float*)d_in[9];
    const float* bv   = (const float*)d_in[10];
    float* out = (float*)d_out;

    unsigned short* xb  = (unsigned short*)d_ws;
    unsigned short* Qb  = xb + (size_t)BS_TOT * DIM;
    unsigned short* Kb  = Qb + (size_t)BS_TOT * DIM;
    unsigned short* VTb = Kb + (size_t)BS_TOT * DIM;
    unsigned short* Wqb = VTb + (size_t)BS_TOT * DIM;
    unsigned short* Wkb = Wqb + DIM * DIM;
    unsigned short* Wvb = Wkb + DIM * DIM;
    float* trigp = (float*)(Wvb + DIM * DIM);                  // 16384 x 4 f32
    unsigned short* Pbuf = (unsigned short*)(trigp + (size_t)BS_TOT * 4);  // 67 MB
    float* Lc = (float*)(Pbuf + (size_t)BS_TOT * SEQ);         // 16384 x 32
    float* Srow = Lc + (size_t)BS_TOT * 32;                    // 16384

    conv_all<<<(NX4 + 3 * NW4) / 256, 256, 0, stream>>>(
        x, Wq, Wk, Wv, xb, Wqb, Wkb, Wvb);
    trig_prep<<<(BS_TOT + 255) / 256, 256, 0, stream>>>(lat, lon, tseq, mk, trigp);

    qkv_gemm<<<dim3(BS_TOT / 128, 12), 256, 0, stream>>>(
        xb, Wqb, Wkb, Wvb, bq, bk, bv, Qb, Kb, VTb);

    score_kernel<<<dim3((SEQ / 128) * (SEQ / 128) * BSZ), 256, 0, stream>>>(
        Qb, Kb, trigp, Pbuf, Lc);
    rowinv<<<(BS_TOT + 255) / 256, 256, 0, stream>>>(Lc, Srow);
    pv_kernel<<<dim3((SEQ / 128) * (DIM / 64) * BSZ), 256, 0, stream>>>(Pbuf, VTb, Srow, out);
}

// Round 10
// 253.977 us; speedup vs baseline: 1.0594x; 1.0594x over previous
//
#include <hip/hip_runtime.h>
#include <math.h>

typedef __attribute__((ext_vector_type(8))) short bf16x8;
typedef __attribute__((ext_vector_type(4))) float f32x4;
typedef __attribute__((ext_vector_type(8))) unsigned short u16x8;

#define BSZ 8
#define SEQ 2048
#define DIM 512
#define BS_TOT (BSZ*SEQ)
#define NX4 (BS_TOT * DIM / 4)
#define NW4 (DIM * DIM / 4)

__device__ __forceinline__ unsigned short f2bf(float f) {
    unsigned int u = __float_as_uint(f);
    unsigned int r = (u + 0x7fffu + ((u >> 16) & 1u)) >> 16;
    return (unsigned short)r;
}

__device__ __forceinline__ f32x4 mfma16(bf16x8 a, bf16x8 b, f32x4 c) {
    return __builtin_amdgcn_mfma_f32_16x16x32_bf16(a, b, c, 0, 0, 0);
}

// Stage a [R rows x 64 cols] bf16 tile into LDS via async global_load_lds (16B/lane).
// XOR-swizzle: LDS slot c holds global chunk c ^ (row&7). R multiple of 32.
#define STAGE64(gbase, rstride, ldsbase, R)                                        \
    {                                                                              \
        _Pragma("unroll")                                                          \
        for (int t_ = 0; t_ < (R) / 32; ++t_) {                                    \
            int r8_ = wave * ((R) / 32) + t_;                                      \
            int row_ = r8_ * 8 + (lane >> 3);                                      \
            int kch_ = (lane & 7) ^ (row_ & 7);                                    \
            const unsigned short* gp_ = (gbase) + (size_t)row_ * (rstride) + kch_ * 8; \
            __builtin_amdgcn_global_load_lds(                                      \
                (const __attribute__((address_space(1))) unsigned int*)gp_,        \
                (__attribute__((address_space(3))) unsigned int*)((ldsbase) + r8_ * 512), \
                16, 0, 0);                                                         \
        }                                                                          \
    }

__device__ __forceinline__ bf16x8 frag_ld(const unsigned short* lds, int row, int kc) {
    return *(const bf16x8*)(lds + row * 64 + (((kc) ^ (row & 7)) << 3));
}

// ---------------- fused fp32 -> bf16 conversion (x, Wq, Wk, Wv in one grid) ----------------
__global__ __launch_bounds__(256) void conv_all(
    const float* __restrict__ x, const float* __restrict__ wq,
    const float* __restrict__ wk, const float* __restrict__ wv,
    unsigned short* __restrict__ xb, unsigned short* __restrict__ wqb,
    unsigned short* __restrict__ wkb, unsigned short* __restrict__ wvb) {
    int i = blockIdx.x * 256 + threadIdx.x;
    const float* s; unsigned short* d; int j;
    if (i < NX4)                { s = x;  d = xb;  j = i; }
    else if (i < NX4 + NW4)     { s = wq; d = wqb; j = i - NX4; }
    else if (i < NX4 + 2 * NW4) { s = wk; d = wkb; j = i - NX4 - NW4; }
    else                        { s = wv; d = wvb; j = i - NX4 - 2 * NW4; }
    float4 v = ((const float4*)s)[j];
    ushort4 o;
    o.x = f2bf(v.x); o.y = f2bf(v.y); o.z = f2bf(v.z); o.w = f2bf(v.w);
    ((ushort4*)d)[j] = o;
}

// ---------------- per-point attr table: 3D unit vector + log2-scaled time ----------------
// {x, y, z, t*log2e}; masked points get t-sentinel 1e9 -> score ~ -1.4e9 -> exp2 -> 0.
__global__ __launch_bounds__(256) void trig_prep(const float* __restrict__ lat,
                                                 const float* __restrict__ lon,
                                                 const float* __restrict__ tm,
                                                 const int* __restrict__ mask,
                                                 float* __restrict__ trigp) {
    int i = blockIdx.x * blockDim.x + threadIdx.x;
    if (i < BS_TOT) {
        const float RAD = 0.017453292519943295f;
        const float LOG2E = 1.442695041f;
        float la = lat[i] * RAD, lo = lon[i] * RAD;
        float cla = cosf(la);
        float4 o = {cla * cosf(lo), cla * sinf(lo), sinf(la),
                    mask[i] ? tm[i] * LOG2E : 1e9f};
        ((float4*)trigp)[i] = o;
    }
}

// ---------------- QKV projection GEMM: one 128x128 tile of one output ----------------
// grid (BS_TOT/128, 12): y -> (o = y>>2, n0 = (y&3)*128)
// o==2 (V): epilogue transposes the tile through LDS so the V^T store is
// 16B/lane, 256B-contiguous per 16 lanes. LDS reused: Ts aliases As|Bs.
// launch_bounds (256,4): 4 blocks/CU co-resident to hide barrier drains.
__global__ __launch_bounds__(256, 4) void qkv_gemm(
    const unsigned short* __restrict__ xb,
    const unsigned short* __restrict__ Wqb, const unsigned short* __restrict__ Wkb,
    const unsigned short* __restrict__ Wvb,
    const float* __restrict__ bq, const float* __restrict__ bk, const float* __restrict__ bv,
    unsigned short* __restrict__ Qb, unsigned short* __restrict__ Kb,
    unsigned short* __restrict__ VTb) {
    __shared__ __align__(16) unsigned short smem[128 * 128];   // 32 KB
    unsigned short* const As = smem;               // [128*64]
    unsigned short* const Bs = smem + 128 * 64;    // [128*64]

    const int tid = threadIdx.x, lane = tid & 63, wave = tid >> 6;
    const int lq = lane & 15, quad = lane >> 4;
    const int w0 = wave & 1, w1 = wave >> 1;
    const int m0 = blockIdx.x * 128;
    const int o = blockIdx.y >> 2, n0 = (blockIdx.y & 3) * 128;
    const unsigned short* W = (o == 0) ? Wqb : (o == 1) ? Wkb : Wvb;
    const float* bias = (o == 0) ? bq : (o == 1) ? bk : bv;

    f32x4 acc[4][4];
    #pragma unroll
    for (int mi = 0; mi < 4; ++mi)
        #pragma unroll
        for (int ni = 0; ni < 4; ++ni) acc[mi][ni] = (f32x4){0.f, 0.f, 0.f, 0.f};

    const unsigned short* Ag = xb + (size_t)m0 * DIM;
    const unsigned short* Bg = W + (size_t)n0 * DIM;

    for (int kc = 0; kc < 8; ++kc) {
        __syncthreads();
        STAGE64(Ag + kc * 64, DIM, As, 128);
        STAGE64(Bg + kc * 64, DIM, Bs, 128);
        __syncthreads();
        #pragma unroll
        for (int ks = 0; ks < 2; ++ks) {
            bf16x8 af[4], bfr[4];
            #pragma unroll
            for (int mi = 0; mi < 4; ++mi) af[mi] = frag_ld(As, w0 * 64 + mi * 16 + lq, ks * 4 + quad);
            #pragma unroll
            for (int ni = 0; ni < 4; ++ni) bfr[ni] = frag_ld(Bs, w1 * 64 + ni * 16 + lq, ks * 4 + quad);
            #pragma unroll
            for (int mi = 0; mi < 4; ++mi)
                #pragma unroll
                for (int ni = 0; ni < 4; ++ni)
                    acc[mi][ni] = mfma16(af[mi], bfr[ni], acc[mi][ni]);
        }
    }

    if (o < 2) {
        unsigned short* G = (o == 0) ? Qb : Kb;
        #pragma unroll
        for (int ni = 0; ni < 4; ++ni) {
            int e = n0 + w1 * 64 + ni * 16 + lq;
            float be = bias[e];
            #pragma unroll
            for (int mi = 0; mi < 4; ++mi)
                #pragma unroll
                for (int r = 0; r < 4; ++r) {
                    int mrow = m0 + w0 * 64 + mi * 16 + quad * 4 + r;
                    G[(size_t)mrow * DIM + e] = f2bf(acc[mi][ni][r] + be);
                }
        }
    } else {
        // ---- V: transpose through LDS, coalesced V^T store ----
        __syncthreads();   // all waves done reading As/Bs
        #pragma unroll
        for (int ni = 0; ni < 4; ++ni) {
            int e = w1 * 64 + ni * 16 + lq;
            float be = bias[n0 + e];
            #pragma unroll
            for (int mi = 0; mi < 4; ++mi) {
                int s = w0 * 64 + mi * 16 + quad * 4;
                ushort4 pk;
                pk.x = f2bf(acc[mi][ni][0] + be);
                pk.y = f2bf(acc[mi][ni][1] + be);
                pk.z = f2bf(acc[mi][ni][2] + be);
                pk.w = f2bf(acc[mi][ni][3] + be);
                int addr = (e * 256 + s * 2) ^ ((e & 7) << 4);
                *(ushort4*)((char*)smem + addr) = pk;
            }
        }
        __syncthreads();
        const int bb = m0 >> 11, sbase = m0 & 2047;
        #pragma unroll
        for (int p = 0; p < 8; ++p) {
            int e = p * 16 + (tid >> 4);
            int s0 = (tid & 15) * 8;
            int addr = (e * 256 + s0 * 2) ^ ((e & 7) << 4);
            u16x8 v = *(const u16x8*)((const char*)smem + addr);
            *(u16x8*)&VTb[((size_t)bb * DIM + n0 + e) * SEQ + sbase + s0] = v;
        }
    }
}

// ---------------- phase 1: 128x128 score tile, NO-SHIFT softmax + distance screen ----------------
// Screen (exactness-preserving): asin(u) >= u => s2 <= qkS - HQ*sqrt(ch2) - dt.
// Skip iff ch2 > t^2, t = (qkS - dt + 160)/HQ => true s2 < -160 => exp2 -> 0.0f.
// KEY FIX vs round 9: screened subtiles write NOTHING (Pbuf pre-zeroed by
// memset) -> no partial-sector store storm, no L2 thrash. ~97% of subtiles
// skip all math AND all stores. Masked keys (huge dt) never screen.
// grid: 1D 2048, b = id&7 -> one batch per XCD.
__global__ __launch_bounds__(256, 3) void score_kernel(
    const unsigned short* __restrict__ Qb, const unsigned short* __restrict__ Kb,
    const float* __restrict__ trigp, unsigned short* __restrict__ Pbuf,
    float* __restrict__ Lc) {
    __shared__ __align__(16) unsigned short As[128 * 64];
    __shared__ __align__(16) unsigned short Bs[128 * 64];

    const int tid = threadIdx.x, lane = tid & 63, wave = tid >> 6;
    const int lq = lane & 15, quad = lane >> 4;
    const int w0 = wave & 1, w1 = wave >> 1;
    const int id = blockIdx.x;
    const int b = id & 7, t = id >> 3;
    const int it = t & 15, jt = t >> 4;
    const int i0 = it * 128, j0 = jt * 128;
    const size_t rowQ = (size_t)b * SEQ + i0;
    const size_t rowK = (size_t)b * SEQ + j0;

    f32x4 acc[4][4];
    #pragma unroll
    for (int mi = 0; mi < 4; ++mi)
        #pragma unroll
        for (int ni = 0; ni < 4; ++ni) acc[mi][ni] = (f32x4){0.f, 0.f, 0.f, 0.f};

    const unsigned short* Ag = Qb + rowQ * DIM;
    const unsigned short* Bg = Kb + rowK * DIM;

    for (int kc = 0; kc < 8; ++kc) {
        __syncthreads();
        STAGE64(Ag + kc * 64, DIM, As, 128);
        STAGE64(Bg + kc * 64, DIM, Bs, 128);
        __syncthreads();
        #pragma unroll
        for (int ks = 0; ks < 2; ++ks) {
            bf16x8 af[4], bfr[4];
            #pragma unroll
            for (int mi = 0; mi < 4; ++mi) af[mi] = frag_ld(As, w0 * 64 + mi * 16 + lq, ks * 4 + quad);
            #pragma unroll
            for (int ni = 0; ni < 4; ++ni) bfr[ni] = frag_ld(Bs, w1 * 64 + ni * 16 + lq, ks * 4 + quad);
            #pragma unroll
            for (int mi = 0; mi < 4; ++mi)
                #pragma unroll
                for (int ni = 0; ni < 4; ++ni)
                    acc[mi][ni] = mfma16(af[mi], bfr[ni], acc[mi][ni]);
        }
    }

    // ---- constants (all folded with log2e) ----
    const float SC2 = 0.04419417382415922f * 1.442695041f;   // (1/sqrt(512))*log2e
    const float KQ = 12742.0f * 1.442695041f;                // 2R*log2e
    const float KHPI = 12742.0f * 1.442695041f * 1.5707963268f;
    const float INVHQ = 1.0f / (6371.0f * 1.442695041f);     // 1/(R*log2e)
    const float C160 = 160.0f * INVHQ;
    // A&S 4.4.47: asin(u) = pi/2 - sqrt(1-u)*P(u), |eps| <= 2e-8
    const float A0 = 1.5707963050f, A1 = -0.2145988016f, A2 = 0.0889789874f,
                A3 = -0.0501743046f, A4 = 0.0308918810f, A5 = -0.0170881256f,
                A6 = 0.0066700901f, A7 = -0.0012624911f;

    // ---- fused sweep: screen -> (bias -> exp2 -> store) -> partial row sum ----
    float sm[16];
    #pragma unroll
    for (int i = 0; i < 16; ++i) sm[i] = 0.f;

    float4 ka[4];
    #pragma unroll
    for (int ni = 0; ni < 4; ++ni)
        ka[ni] = ((const float4*)trigp)[rowK + w1 * 64 + ni * 16 + lq];

    #pragma unroll
    for (int mi = 0; mi < 4; ++mi) {
        float4 qa[4];
        #pragma unroll
        for (int r = 0; r < 4; ++r)
            qa[r] = ((const float4*)trigp)[rowQ + w0 * 64 + mi * 16 + quad * 4 + r];
        #pragma unroll
        for (int ni = 0; ni < 4; ++ni) {
            float4 k = ka[ni];
            float c2[4], dtv[4], qkS[4];
            int need = 0;
            #pragma unroll
            for (int r = 0; r < 4; ++r) {
                float dx = qa[r].x - k.x;
                float dy = qa[r].y - k.y;
                float dz = qa[r].z - k.z;
                c2[r] = fmaf(dx, dx, fmaf(dy, dy, dz * dz));   // chord^2
                qkS[r] = acc[mi][ni][r] * SC2;
                dtv[r] = fabsf(k.w - qa[r].w);
                float tt = fmaf(qkS[r] - dtv[r], INVHQ, C160);
                need |= (c2[r] <= tt * tt) ? 1 : 0;
            }
            if (__any(need)) {
                #pragma unroll
                for (int r = 0; r < 4; ++r) {
                    float u = fminf(0.5f * __builtin_amdgcn_sqrtf(c2[r]), 1.0f);
                    float vv = __builtin_amdgcn_sqrtf(1.0f - u);
                    float pl = fmaf(A7, u, A6);
                    pl = fmaf(pl, u, A5); pl = fmaf(pl, u, A4); pl = fmaf(pl, u, A3);
                    pl = fmaf(pl, u, A2); pl = fmaf(pl, u, A1); pl = fmaf(pl, u, A0);
                    float sv = fmaf(vv * pl, KQ, qkS[r] - KHPI) - dtv[r];
                    float p = __builtin_amdgcn_exp2f(sv);
                    sm[mi * 4 + r] += p;
                    Pbuf[(rowQ + w0 * 64 + mi * 16 + quad * 4 + r) * SEQ + j0 +
                         w1 * 64 + ni * 16 + lq] = f2bf(p);
                }
            }
            // screened: Pbuf already zero from memset -> no store, no math
        }
    }
    #pragma unroll
    for (int o = 1; o < 16; o <<= 1)
        #pragma unroll
        for (int i = 0; i < 16; ++i) sm[i] += __shfl_xor(sm[i], o);

    if (lq == 0) {
        int chunk = jt * 2 + w1;
        #pragma unroll
        for (int mi = 0; mi < 4; ++mi)
            #pragma unroll
            for (int r = 0; r < 4; ++r) {
                size_t g = rowQ + w0 * 64 + mi * 16 + quad * 4 + r;
                Lc[g * 32 + chunk] = sm[mi * 4 + r];
            }
    }
}

// ---------------- phase 1.5: per-row 1/L + nonzero-chunk bitmask ----------------
__global__ __launch_bounds__(256) void rowinv(
    const float* __restrict__ Lc, float* __restrict__ Srow,
    unsigned int* __restrict__ rowmask) {
    int g = blockIdx.x * 256 + threadIdx.x;
    if (g >= BS_TOT) return;
    float L = 0.f;
    unsigned int m = 0;
    #pragma unroll
    for (int c = 0; c < 32; ++c) {
        float v = Lc[(size_t)g * 32 + c];
        L += v;
        if (v != 0.0f) m |= (1u << c);
    }
    Srow[g] = 1.0f / L;
    rowmask[g] = m;
}

// ---------------- phase 2: O = Srow * (P V) with zero-chunk skipping ----------------
// 128x64 tile, 1024 blocks = 4/CU. Per block: OR the 128 row masks -> skip
// staging+MFMA for 64-key chunks whose P columns are entirely zero (exact:
// dropped terms contribute +0.0). ~50% of chunks skip at this granularity.
// grid: 1D 1024, b = id&7 -> batch-per-XCD.
__global__ __launch_bounds__(256, 4) void pv_kernel(
    const unsigned short* __restrict__ Pbuf, const unsigned short* __restrict__ VTb,
    const float* __restrict__ Srow, const unsigned int* __restrict__ rowmask,
    float* __restrict__ Out) {
    __shared__ __align__(16) unsigned short As[128 * 64];
    __shared__ __align__(16) unsigned short Bs[64 * 64];
    __shared__ unsigned int msk[128];

    const int tid = threadIdx.x, lane = tid & 63, wave = tid >> 6;
    const int lq = lane & 15, quad = lane >> 4;
    const int id = blockIdx.x;
    const int b = id & 7, t = id >> 3;
    const int d0 = (t & 7) * 64, i0 = (t >> 3) * 128;

    if (tid < 128) msk[tid] = rowmask[(size_t)b * SEQ + i0 + tid];
    __syncthreads();
    if (tid < 64) msk[tid] |= msk[tid + 64];
    __syncthreads();
    if (tid < 32) msk[tid] |= msk[tid + 32];
    __syncthreads();
    if (tid < 16) msk[tid] |= msk[tid + 16];
    __syncthreads();
    if (tid < 8) msk[tid] |= msk[tid + 8];
    __syncthreads();
    if (tid < 4) msk[tid] |= msk[tid + 4];
    __syncthreads();
    if (tid < 2) msk[tid] |= msk[tid + 2];
    __syncthreads();
    if (tid == 0) msk[0] |= msk[1];
    __syncthreads();
    const unsigned int cmask = msk[0];

    f32x4 acc[2][4];
    #pragma unroll
    for (int mi = 0; mi < 2; ++mi)
        #pragma unroll
        for (int ni = 0; ni < 4; ++ni) acc[mi][ni] = (f32x4){0.f, 0.f, 0.f, 0.f};

    const unsigned short* Ag = Pbuf + ((size_t)b * SEQ + i0) * SEQ;
    const unsigned short* Bg = VTb + ((size_t)b * DIM + d0) * SEQ;

    #pragma unroll 1
    for (int kc = 0; kc < 32; ++kc) {
        if (!((cmask >> kc) & 1u)) continue;   // whole 64-key chunk is zero P
        __syncthreads();
        STAGE64(Ag + kc * 64, SEQ, As, 128);
        STAGE64(Bg + kc * 64, SEQ, Bs, 64);
        __syncthreads();
        #pragma unroll
        for (int ks = 0; ks < 2; ++ks) {
            bf16x8 af[2], bfr[4];
            #pragma unroll
            for (int mi = 0; mi < 2; ++mi) af[mi] = frag_ld(As, wave * 32 + mi * 16 + lq, ks * 4 + quad);
            #pragma unroll
            for (int ni = 0; ni < 4; ++ni) bfr[ni] = frag_ld(Bs, ni * 16 + lq, ks * 4 + quad);
            #pragma unroll
            for (int mi = 0; mi < 2; ++mi)
                #pragma unroll
                for (int ni = 0; ni < 4; ++ni)
                    acc[mi][ni] = mfma16(af[mi], bfr[ni], acc[mi][ni]);
        }
    }

    #pragma unroll
    for (int mi = 0; mi < 2; ++mi)
        #pragma unroll
        for (int r = 0; r < 4; ++r) {
            size_t grow = (size_t)b * SEQ + i0 + wave * 32 + mi * 16 + quad * 4 + r;
            float s = Srow[grow];
            size_t orow = grow * DIM;
            #pragma unroll
            for (int ni = 0; ni < 4; ++ni)
                Out[orow + d0 + ni * 16 + lq] = acc[mi][ni][r] * s;
        }
}

extern "C" void kernel_launch(void* const* d_in, const int* in_sizes, int n_in,
                              void* d_out, int out_size, void* d_ws, size_t ws_size,
                              hipStream_t stream) {
    (void)in_sizes; (void)n_in; (void)out_size; (void)ws_size;
    const float* x    = (const float*)d_in[0];
    const float* tseq = (const float*)d_in[1];
    const float* lat  = (const float*)d_in[2];
    const float* lon  = (const float*)d_in[3];
    const int*   mk   = (const int*)d_in[4];
    const float* Wq   = (const float*)d_in[5];
    const float* bq   = (const float*)d_in[6];
    const float* Wk   = (const float*)d_in[7];
    const float* bk   = (const float*)d_in[8];
    const float* Wv   = (const float*)d_in[9];
    const float* bv   = (const float*)d_in[10];
    float* out = (float*)d_out;

    unsigned short* xb  = (unsigned short*)d_ws;
    unsigned short* Qb  = xb + (size_t)BS_TOT * DIM;
    unsigned short* Kb  = Qb + (size_t)BS_TOT * DIM;
    unsigned short* VTb = Kb + (size_t)BS_TOT * DIM;
    unsigned short* Wqb = VTb + (size_t)BS_TOT * DIM;
    unsigned short* Wkb = Wqb + DIM * DIM;
    unsigned short* Wvb = Wkb + DIM * DIM;
    float* trigp = (float*)(Wvb + DIM * DIM);                  // 16384 x 4 f32
    unsigned short* Pbuf = (unsigned short*)(trigp + (size_t)BS_TOT * 4);  // 67 MB
    float* Lc = (float*)(Pbuf + (size_t)BS_TOT * SEQ);         // 16384 x 32
    float* Srow = Lc + (size_t)BS_TOT * 32;                    // 16384
    unsigned int* rowmask = (unsigned int*)(Srow + BS_TOT);    // 16384

    hipMemsetAsync(Pbuf, 0, (size_t)BS_TOT * SEQ * sizeof(unsigned short), stream);

    conv_all<<<(NX4 + 3 * NW4) / 256, 256, 0, stream>>>(
        x, Wq, Wk, Wv, xb, Wqb, Wkb, Wvb);
    trig_prep<<<(BS_TOT + 255) / 256, 256, 0, stream>>>(lat, lon, tseq, mk, trigp);

    qkv_gemm<<<dim3(BS_TOT / 128, 12), 256, 0, stream>>>(
        xb, Wqb, Wkb, Wvb, bq, bk, bv, Qb, Kb, VTb);

    score_kernel<<<dim3((SEQ / 128) * (SEQ / 128) * BSZ), 256, 0, stream>>>(
        Qb, Kb, trigp, Pbuf, Lc);
    rowinv<<<(BS_TOT + 255) / 256, 256, 0, stream>>>(Lc, Srow, rowmask);
    pv_kernel<<<dim3((SEQ / 128) * (DIM / 64) * BSZ), 256, 0, stream>>>(
        Pbuf, VTb, Srow, rowmask, out);
}

// Round 12
// 223.321 us; speedup vs baseline: 1.2048x; 1.1373x over previous
//
#include <hip/hip_runtime.h>
#include <math.h>

typedef __attribute__((ext_vector_type(8))) short bf16x8;
typedef __attribute__((ext_vector_type(4))) float f32x4;
typedef __attribute__((ext_vector_type(8))) unsigned short u16x8;

#define BSZ 8
#define SEQ 2048
#define DIM 512
#define BS_TOT (BSZ*SEQ)
#define NX4 (BS_TOT * DIM / 4)
#define NW4 (DIM * DIM / 4)

__device__ __forceinline__ unsigned short f2bf(float f) {
    unsigned int u = __float_as_uint(f);
    unsigned int r = (u + 0x7fffu + ((u >> 16) & 1u)) >> 16;
    return (unsigned short)r;
}

__device__ __forceinline__ f32x4 mfma16(bf16x8 a, bf16x8 b, f32x4 c) {
    return __builtin_amdgcn_mfma_f32_16x16x32_bf16(a, b, c, 0, 0, 0);
}

// Stage a [R rows x 64 cols] bf16 tile into LDS via async global_load_lds (16B/lane).
// XOR-swizzle: LDS slot c holds global chunk c ^ (row&7). R multiple of 32.
#define STAGE64(gbase, rstride, ldsbase, R)                                        \
    {                                                                              \
        _Pragma("unroll")                                                          \
        for (int t_ = 0; t_ < (R) / 32; ++t_) {                                    \
            int r8_ = wave * ((R) / 32) + t_;                                      \
            int row_ = r8_ * 8 + (lane >> 3);                                      \
            int kch_ = (lane & 7) ^ (row_ & 7);                                    \
            const unsigned short* gp_ = (gbase) + (size_t)row_ * (rstride) + kch_ * 8; \
            __builtin_amdgcn_global_load_lds(                                      \
                (const __attribute__((address_space(1))) unsigned int*)gp_,        \
                (__attribute__((address_space(3))) unsigned int*)((ldsbase) + r8_ * 512), \
                16, 0, 0);                                                         \
        }                                                                          \
    }

__device__ __forceinline__ bf16x8 frag_ld(const unsigned short* lds, int row, int kc) {
    return *(const bf16x8*)(lds + row * 64 + (((kc) ^ (row & 7)) << 3));
}

// ---------------- fused fp32 -> bf16 conversion (x, Wq, Wk, Wv in one grid) ----------------
__global__ __launch_bounds__(256) void conv_all(
    const float* __restrict__ x, const float* __restrict__ wq,
    const float* __restrict__ wk, const float* __restrict__ wv,
    unsigned short* __restrict__ xb, unsigned short* __restrict__ wqb,
    unsigned short* __restrict__ wkb, unsigned short* __restrict__ wvb) {
    int i = blockIdx.x * 256 + threadIdx.x;
    const float* s; unsigned short* d; int j;
    if (i < NX4)                { s = x;  d = xb;  j = i; }
    else if (i < NX4 + NW4)     { s = wq; d = wqb; j = i - NX4; }
    else if (i < NX4 + 2 * NW4) { s = wk; d = wkb; j = i - NX4 - NW4; }
    else                        { s = wv; d = wvb; j = i - NX4 - 2 * NW4; }
    float4 v = ((const float4*)s)[j];
    ushort4 o;
    o.x = f2bf(v.x); o.y = f2bf(v.y); o.z = f2bf(v.z); o.w = f2bf(v.w);
    ((ushort4*)d)[j] = o;
}

// ---------------- per-point attr table: 3D unit vector + log2-scaled time ----------------
// {x, y, z, t*log2e}; masked points get t-sentinel 1e9 -> score ~ -1.4e9 -> exp2 -> 0.
__global__ __launch_bounds__(256) void trig_prep(const float* __restrict__ lat,
                                                 const float* __restrict__ lon,
                                                 const float* __restrict__ tm,
                                                 const int* __restrict__ mask,
                                                 float* __restrict__ trigp) {
    int i = blockIdx.x * blockDim.x + threadIdx.x;
    if (i < BS_TOT) {
        const float RAD = 0.017453292519943295f;
        const float LOG2E = 1.442695041f;
        float la = lat[i] * RAD, lo = lon[i] * RAD;
        float cla = cosf(la);
        float4 o = {cla * cosf(lo), cla * sinf(lo), sinf(la),
                    mask[i] ? tm[i] * LOG2E : 1e9f};
        ((float4*)trigp)[i] = o;
    }
}

// ---------------- QKV projection GEMM: one 128x128 tile of one output ----------------
// grid (BS_TOT/128, 12): y -> (o = y>>2, n0 = (y&3)*128)
// o==2 (V): epilogue transposes the tile through LDS so the V^T store is
// 16B/lane, 256B-contiguous per 16 lanes. LDS reused: Ts aliases As|Bs.
// launch_bounds (256,4): 4 blocks/CU co-resident to hide barrier drains.
__global__ __launch_bounds__(256, 4) void qkv_gemm(
    const unsigned short* __restrict__ xb,
    const unsigned short* __restrict__ Wqb, const unsigned short* __restrict__ Wkb,
    const unsigned short* __restrict__ Wvb,
    const float* __restrict__ bq, const float* __restrict__ bk, const float* __restrict__ bv,
    unsigned short* __restrict__ Qb, unsigned short* __restrict__ Kb,
    unsigned short* __restrict__ VTb) {
    __shared__ __align__(16) unsigned short smem[128 * 128];   // 32 KB
    unsigned short* const As = smem;               // [128*64]
    unsigned short* const Bs = smem + 128 * 64;    // [128*64]

    const int tid = threadIdx.x, lane = tid & 63, wave = tid >> 6;
    const int lq = lane & 15, quad = lane >> 4;
    const int w0 = wave & 1, w1 = wave >> 1;
    const int m0 = blockIdx.x * 128;
    const int o = blockIdx.y >> 2, n0 = (blockIdx.y & 3) * 128;
    const unsigned short* W = (o == 0) ? Wqb : (o == 1) ? Wkb : Wvb;
    const float* bias = (o == 0) ? bq : (o == 1) ? bk : bv;

    f32x4 acc[4][4];
    #pragma unroll
    for (int mi = 0; mi < 4; ++mi)
        #pragma unroll
        for (int ni = 0; ni < 4; ++ni) acc[mi][ni] = (f32x4){0.f, 0.f, 0.f, 0.f};

    const unsigned short* Ag = xb + (size_t)m0 * DIM;
    const unsigned short* Bg = W + (size_t)n0 * DIM;

    for (int kc = 0; kc < 8; ++kc) {
        __syncthreads();
        STAGE64(Ag + kc * 64, DIM, As, 128);
        STAGE64(Bg + kc * 64, DIM, Bs, 128);
        __syncthreads();
        #pragma unroll
        for (int ks = 0; ks < 2; ++ks) {
            bf16x8 af[4], bfr[4];
            #pragma unroll
            for (int mi = 0; mi < 4; ++mi) af[mi] = frag_ld(As, w0 * 64 + mi * 16 + lq, ks * 4 + quad);
            #pragma unroll
            for (int ni = 0; ni < 4; ++ni) bfr[ni] = frag_ld(Bs, w1 * 64 + ni * 16 + lq, ks * 4 + quad);
            #pragma unroll
            for (int mi = 0; mi < 4; ++mi)
                #pragma unroll
                for (int ni = 0; ni < 4; ++ni)
                    acc[mi][ni] = mfma16(af[mi], bfr[ni], acc[mi][ni]);
        }
    }

    if (o < 2) {
        unsigned short* G = (o == 0) ? Qb : Kb;
        #pragma unroll
        for (int ni = 0; ni < 4; ++ni) {
            int e = n0 + w1 * 64 + ni * 16 + lq;
            float be = bias[e];
            #pragma unroll
            for (int mi = 0; mi < 4; ++mi)
                #pragma unroll
                for (int r = 0; r < 4; ++r) {
                    int mrow = m0 + w0 * 64 + mi * 16 + quad * 4 + r;
                    G[(size_t)mrow * DIM + e] = f2bf(acc[mi][ni][r] + be);
                }
        }
    } else {
        // ---- V: transpose through LDS, coalesced V^T store ----
        __syncthreads();   // all waves done reading As/Bs
        #pragma unroll
        for (int ni = 0; ni < 4; ++ni) {
            int e = w1 * 64 + ni * 16 + lq;
            float be = bias[n0 + e];
            #pragma unroll
            for (int mi = 0; mi < 4; ++mi) {
                int s = w0 * 64 + mi * 16 + quad * 4;
                ushort4 pk;
                pk.x = f2bf(acc[mi][ni][0] + be);
                pk.y = f2bf(acc[mi][ni][1] + be);
                pk.z = f2bf(acc[mi][ni][2] + be);
                pk.w = f2bf(acc[mi][ni][3] + be);
                int addr = (e * 256 + s * 2) ^ ((e & 7) << 4);
                *(ushort4*)((char*)smem + addr) = pk;
            }
        }
        __syncthreads();
        const int bb = m0 >> 11, sbase = m0 & 2047;
        #pragma unroll
        for (int p = 0; p < 8; ++p) {
            int e = p * 16 + (tid >> 4);
            int s0 = (tid & 15) * 8;
            int addr = (e * 256 + s0 * 2) ^ ((e & 7) << 4);
            u16x8 v = *(const u16x8*)((const char*)smem + addr);
            *(u16x8*)&VTb[((size_t)bb * DIM + n0 + e) * SEQ + sbase + s0] = v;
        }
    }
}

// ---------------- phase 1: 128x128 score tile, NO-SHIFT softmax + screen + LDS-staged P ----------------
// Screen (exactness-preserving): asin(u) >= u => s2 <= qkS - HQ*sqrt(ch2) - dt.
// Skip iff ch2 > t^2, t = (qkS - dt + 160)/HQ => true s2 < -160 => exp2 -> 0 in
// f32/bf16 and invisible in the f32 row sum. Fast path computes p=0 with ZERO
// transcendentals (~97% of subtiles).
// KEY FIX vs rounds 9/10: P tile is staged in LDS (reusing As|Bs = exactly
// 128x128 bf16) and flushed with 16B/lane 256B-contiguous full-line stores —
// the HBM write pattern is dense and coalesced REGARDLESS of screen outcome.
// No memset needed (full tile always written).
// grid: 1D 2048, b = id&7 -> one batch per XCD.
__global__ __launch_bounds__(256, 3) void score_kernel(
    const unsigned short* __restrict__ Qb, const unsigned short* __restrict__ Kb,
    const float* __restrict__ trigp, unsigned short* __restrict__ Pbuf,
    float* __restrict__ Lc) {
    __shared__ __align__(16) unsigned short smem[128 * 128];   // 32 KB
    unsigned short* const As = smem;               // [128*64]
    unsigned short* const Bs = smem + 128 * 64;    // [128*64]

    const int tid = threadIdx.x, lane = tid & 63, wave = tid >> 6;
    const int lq = lane & 15, quad = lane >> 4;
    const int w0 = wave & 1, w1 = wave >> 1;
    const int id = blockIdx.x;
    const int b = id & 7, t = id >> 3;
    const int it = t & 15, jt = t >> 4;
    const int i0 = it * 128, j0 = jt * 128;
    const size_t rowQ = (size_t)b * SEQ + i0;
    const size_t rowK = (size_t)b * SEQ + j0;

    f32x4 acc[4][4];
    #pragma unroll
    for (int mi = 0; mi < 4; ++mi)
        #pragma unroll
        for (int ni = 0; ni < 4; ++ni) acc[mi][ni] = (f32x4){0.f, 0.f, 0.f, 0.f};

    const unsigned short* Ag = Qb + rowQ * DIM;
    const unsigned short* Bg = Kb + rowK * DIM;

    for (int kc = 0; kc < 8; ++kc) {
        __syncthreads();
        STAGE64(Ag + kc * 64, DIM, As, 128);
        STAGE64(Bg + kc * 64, DIM, Bs, 128);
        __syncthreads();
        #pragma unroll
        for (int ks = 0; ks < 2; ++ks) {
            bf16x8 af[4], bfr[4];
            #pragma unroll
            for (int mi = 0; mi < 4; ++mi) af[mi] = frag_ld(As, w0 * 64 + mi * 16 + lq, ks * 4 + quad);
            #pragma unroll
            for (int ni = 0; ni < 4; ++ni) bfr[ni] = frag_ld(Bs, w1 * 64 + ni * 16 + lq, ks * 4 + quad);
            #pragma unroll
            for (int mi = 0; mi < 4; ++mi)
                #pragma unroll
                for (int ni = 0; ni < 4; ++ni)
                    acc[mi][ni] = mfma16(af[mi], bfr[ni], acc[mi][ni]);
        }
    }
    __syncthreads();   // all frag reads done; smem is now the P staging tile

    // ---- constants (all folded with log2e) ----
    const float SC2 = 0.04419417382415922f * 1.442695041f;   // (1/sqrt(512))*log2e
    const float KQ = 12742.0f * 1.442695041f;                // 2R*log2e
    const float KHPI = 12742.0f * 1.442695041f * 1.5707963268f;
    const float INVHQ = 1.0f / (6371.0f * 1.442695041f);     // 1/(R*log2e)
    const float C160 = 160.0f * INVHQ;
    // A&S 4.4.47: asin(u) = pi/2 - sqrt(1-u)*P(u), |eps| <= 2e-8
    const float A0 = 1.5707963050f, A1 = -0.2145988016f, A2 = 0.0889789874f,
                A3 = -0.0501743046f, A4 = 0.0308918810f, A5 = -0.0170881256f,
                A6 = 0.0066700901f, A7 = -0.0012624911f;

    // ---- fused sweep: screen -> p (0 or exp2) -> LDS stage -> partial row sum ----
    float sm[16];
    #pragma unroll
    for (int i = 0; i < 16; ++i) sm[i] = 0.f;

    float4 ka[4];
    #pragma unroll
    for (int ni = 0; ni < 4; ++ni)
        ka[ni] = ((const float4*)trigp)[rowK + w1 * 64 + ni * 16 + lq];

    #pragma unroll
    for (int mi = 0; mi < 4; ++mi) {
        float4 qa[4];
        #pragma unroll
        for (int r = 0; r < 4; ++r)
            qa[r] = ((const float4*)trigp)[rowQ + w0 * 64 + mi * 16 + quad * 4 + r];
        #pragma unroll
        for (int ni = 0; ni < 4; ++ni) {
            float4 k = ka[ni];
            float c2[4], dtv[4], qkS[4], p4[4];
            int need = 0;
            #pragma unroll
            for (int r = 0; r < 4; ++r) {
                float dx = qa[r].x - k.x;
                float dy = qa[r].y - k.y;
                float dz = qa[r].z - k.z;
                c2[r] = fmaf(dx, dx, fmaf(dy, dy, dz * dz));   // chord^2
                qkS[r] = acc[mi][ni][r] * SC2;
                dtv[r] = fabsf(k.w - qa[r].w);
                float tt = fmaf(qkS[r] - dtv[r], INVHQ, C160);
                need |= (c2[r] <= tt * tt) ? 1 : 0;
            }
            if (__any(need)) {
                #pragma unroll
                for (int r = 0; r < 4; ++r) {
                    float u = fminf(0.5f * __builtin_amdgcn_sqrtf(c2[r]), 1.0f);
                    float vv = __builtin_amdgcn_sqrtf(1.0f - u);
                    float pl = fmaf(A7, u, A6);
                    pl = fmaf(pl, u, A5); pl = fmaf(pl, u, A4); pl = fmaf(pl, u, A3);
                    pl = fmaf(pl, u, A2); pl = fmaf(pl, u, A1); pl = fmaf(pl, u, A0);
                    float sv = fmaf(vv * pl, KQ, qkS[r] - KHPI) - dtv[r];
                    p4[r] = __builtin_amdgcn_exp2f(sv);
                    sm[mi * 4 + r] += p4[r];
                }
            } else {
                #pragma unroll
                for (int r = 0; r < 4; ++r) p4[r] = 0.f;
            }
            #pragma unroll
            for (int r = 0; r < 4; ++r) {
                int row = w0 * 64 + mi * 16 + quad * 4 + r;
                int col = w1 * 64 + ni * 16 + lq;
                *(unsigned short*)((char*)smem +
                    ((row * 256 + col * 2) ^ ((row & 7) << 4))) = f2bf(p4[r]);
            }
        }
    }
    #pragma unroll
    for (int o = 1; o < 16; o <<= 1)
        #pragma unroll
        for (int i = 0; i < 16; ++i) sm[i] += __shfl_xor(sm[i], o);

    if (lq == 0) {
        int chunk = jt * 2 + w1;
        #pragma unroll
        for (int mi = 0; mi < 4; ++mi)
            #pragma unroll
            for (int r = 0; r < 4; ++r) {
                size_t g = rowQ + w0 * 64 + mi * 16 + quad * 4 + r;
                Lc[g * 32 + chunk] = sm[mi * 4 + r];
            }
    }

    __syncthreads();   // all P values staged in LDS
    // ---- coalesced flush: 16B/lane, 256B contiguous per 16-lane group ----
    #pragma unroll
    for (int pp = 0; pp < 8; ++pp) {
        int row = pp * 16 + (tid >> 4);
        int c0 = (tid & 15) * 8;
        u16x8 v = *(const u16x8*)((const char*)smem +
                                  ((row * 256 + c0 * 2) ^ ((row & 7) << 4)));
        *(u16x8*)&Pbuf[(rowQ + row) * SEQ + j0 + c0] = v;
    }
}

// ---------------- phase 1.5: per-row 1/L + nonzero-chunk bitmask ----------------
__global__ __launch_bounds__(256) void rowinv(
    const float* __restrict__ Lc, float* __restrict__ Srow,
    unsigned int* __restrict__ rowmask) {
    int g = blockIdx.x * 256 + threadIdx.x;
    if (g >= BS_TOT) return;
    float L = 0.f;
    unsigned int m = 0;
    #pragma unroll
    for (int c = 0; c < 32; ++c) {
        float v = Lc[(size_t)g * 32 + c];
        L += v;
        if (v != 0.0f) m |= (1u << c);
    }
    Srow[g] = 1.0f / L;
    rowmask[g] = m;
}

// ---------------- phase 2: O = Srow * (P V) with zero-chunk skipping ----------------
// 128x64 tile, 1024 blocks = 4/CU. Per block: OR the 128 row masks -> skip
// staging+MFMA for 64-key chunks whose P columns are entirely zero (exact:
// dropped terms contribute +0.0).
// grid: 1D 1024, b = id&7 -> batch-per-XCD.
__global__ __launch_bounds__(256, 4) void pv_kernel(
    const unsigned short* __restrict__ Pbuf, const unsigned short* __restrict__ VTb,
    const float* __restrict__ Srow, const unsigned int* __restrict__ rowmask,
    float* __restrict__ Out) {
    __shared__ __align__(16) unsigned short As[128 * 64];
    __shared__ __align__(16) unsigned short Bs[64 * 64];
    __shared__ unsigned int msk[128];

    const int tid = threadIdx.x, lane = tid & 63, wave = tid >> 6;
    const int lq = lane & 15, quad = lane >> 4;
    const int id = blockIdx.x;
    const int b = id & 7, t = id >> 3;
    const int d0 = (t & 7) * 64, i0 = (t >> 3) * 128;

    if (tid < 128) msk[tid] = rowmask[(size_t)b * SEQ + i0 + tid];
    __syncthreads();
    if (tid < 64) msk[tid] |= msk[tid + 64];
    __syncthreads();
    if (tid < 32) msk[tid] |= msk[tid + 32];
    __syncthreads();
    if (tid < 16) msk[tid] |= msk[tid + 16];
    __syncthreads();
    if (tid < 8) msk[tid] |= msk[tid + 8];
    __syncthreads();
    if (tid < 4) msk[tid] |= msk[tid + 4];
    __syncthreads();
    if (tid < 2) msk[tid] |= msk[tid + 2];
    __syncthreads();
    if (tid == 0) msk[0] |= msk[1];
    __syncthreads();
    const unsigned int cmask = msk[0];

    f32x4 acc[2][4];
    #pragma unroll
    for (int mi = 0; mi < 2; ++mi)
        #pragma unroll
        for (int ni = 0; ni < 4; ++ni) acc[mi][ni] = (f32x4){0.f, 0.f, 0.f, 0.f};

    const unsigned short* Ag = Pbuf + ((size_t)b * SEQ + i0) * SEQ;
    const unsigned short* Bg = VTb + ((size_t)b * DIM + d0) * SEQ;

    #pragma unroll 1
    for (int kc = 0; kc < 32; ++kc) {
        if (!((cmask >> kc) & 1u)) continue;   // whole 64-key chunk is zero P
        __syncthreads();
        STAGE64(Ag + kc * 64, SEQ, As, 128);
        STAGE64(Bg + kc * 64, SEQ, Bs, 64);
        __syncthreads();
        #pragma unroll
        for (int ks = 0; ks < 2; ++ks) {
            bf16x8 af[2], bfr[4];
            #pragma unroll
            for (int mi = 0; mi < 2; ++mi) af[mi] = frag_ld(As, wave * 32 + mi * 16 + lq, ks * 4 + quad);
            #pragma unroll
            for (int ni = 0; ni < 4; ++ni) bfr[ni] = frag_ld(Bs, ni * 16 + lq, ks * 4 + quad);
            #pragma unroll
            for (int mi = 0; mi < 2; ++mi)
                #pragma unroll
                for (int ni = 0; ni < 4; ++ni)
                    acc[mi][ni] = mfma16(af[mi], bfr[ni], acc[mi][ni]);
        }
    }

    #pragma unroll
    for (int mi = 0; mi < 2; ++mi)
        #pragma unroll
        for (int r = 0; r < 4; ++r) {
            size_t grow = (size_t)b * SEQ + i0 + wave * 32 + mi * 16 + quad * 4 + r;
            float s = Srow[grow];
            size_t orow = grow * DIM;
            #pragma unroll
            for (int ni = 0; ni < 4; ++ni)
                Out[orow + d0 + ni * 16 + lq] = acc[mi][ni][r] * s;
        }
}

extern "C" void kernel_launch(void* const* d_in, const int* in_sizes, int n_in,
                              void* d_out, int out_size, void* d_ws, size_t ws_size,
                              hipStream_t stream) {
    (void)in_sizes; (void)n_in; (void)out_size; (void)ws_size;
    const float* x    = (const float*)d_in[0];
    const float* tseq = (const float*)d_in[1];
    const float* lat  = (const float*)d_in[2];
    const float* lon  = (const float*)d_in[3];
    const int*   mk   = (const int*)d_in[4];
    const float* Wq   = (const float*)d_in[5];
    const float* bq   = (const float*)d_in[6];
    const float* Wk   = (const float*)d_in[7];
    const float* bk   = (const float*)d_in[8];
    const float* Wv   = (const float*)d_in[9];
    const float* bv   = (const float*)d_in[10];
    float* out = (float*)d_out;

    unsigned short* xb  = (unsigned short*)d_ws;
    unsigned short* Qb  = xb + (size_t)BS_TOT * DIM;
    unsigned short* Kb  = Qb + (size_t)BS_TOT * DIM;
    unsigned short* VTb = Kb + (size_t)BS_TOT * DIM;
    unsigned short* Wqb = VTb + (size_t)BS_TOT * DIM;
    unsigned short* Wkb = Wqb + DIM * DIM;
    unsigned short* Wvb = Wkb + DIM * DIM;
    float* trigp = (float*)(Wvb + DIM * DIM);                  // 16384 x 4 f32
    unsigned short* Pbuf = (unsigned short*)(trigp + (size_t)BS_TOT * 4);  // 67 MB
    float* Lc = (float*)(Pbuf + (size_t)BS_TOT * SEQ);         // 16384 x 32
    float* Srow = Lc + (size_t)BS_TOT * 32;                    // 16384
    unsigned int* rowmask = (unsigned int*)(Srow + BS_TOT);    // 16384

    conv_all<<<(NX4 + 3 * NW4) / 256, 256, 0, stream>>>(
        x, Wq, Wk, Wv, xb, Wqb, Wkb, Wvb);
    trig_prep<<<(BS_TOT + 255) / 256, 256, 0, stream>>>(lat, lon, tseq, mk, trigp);

    qkv_gemm<<<dim3(BS_TOT / 128, 12), 256, 0, stream>>>(
        xb, Wqb, Wkb, Wvb, bq, bk, bv, Qb, Kb, VTb);

    score_kernel<<<dim3((SEQ / 128) * (SEQ / 128) * BSZ), 256, 0, stream>>>(
        Qb, Kb, trigp, Pbuf, Lc);
    rowinv<<<(BS_TOT + 255) / 256, 256, 0, stream>>>(Lc, Srow, rowmask);
    pv_kernel<<<dim3((SEQ / 128) * (DIM / 64) * BSZ), 256, 0, stream>>>(
        Pbuf, VTb, Srow, rowmask, out);
}

// Round 13
// 221.055 us; speedup vs baseline: 1.2172x; 1.0103x over previous
//
#include <hip/hip_runtime.h>
#include <math.h>

typedef __attribute__((ext_vector_type(8))) short bf16x8;
typedef __attribute__((ext_vector_type(4))) float f32x4;
typedef __attribute__((ext_vector_type(8))) unsigned short u16x8;

#define BSZ 8
#define SEQ 2048
#define DIM 512
#define BS_TOT (BSZ*SEQ)
#define NX4 (BS_TOT * DIM / 4)
#define NW4 (DIM * DIM / 4)

__device__ __forceinline__ unsigned short f2bf(float f) {
    unsigned int u = __float_as_uint(f);
    unsigned int r = (u + 0x7fffu + ((u >> 16) & 1u)) >> 16;
    return (unsigned short)r;
}

__device__ __forceinline__ f32x4 mfma16(bf16x8 a, bf16x8 b, f32x4 c) {
    return __builtin_amdgcn_mfma_f32_16x16x32_bf16(a, b, c, 0, 0, 0);
}

// Stage a [R rows x 64 cols] bf16 tile into LDS via async global_load_lds (16B/lane).
// XOR-swizzle: LDS slot c holds global chunk c ^ (row&7). R multiple of 32.
#define STAGE64(gbase, rstride, ldsbase, R)                                        \
    {                                                                              \
        _Pragma("unroll")                                                          \
        for (int t_ = 0; t_ < (R) / 32; ++t_) {                                    \
            int r8_ = wave * ((R) / 32) + t_;                                      \
            int row_ = r8_ * 8 + (lane >> 3);                                      \
            int kch_ = (lane & 7) ^ (row_ & 7);                                    \
            const unsigned short* gp_ = (gbase) + (size_t)row_ * (rstride) + kch_ * 8; \
            __builtin_amdgcn_global_load_lds(                                      \
                (const __attribute__((address_space(1))) unsigned int*)gp_,        \
                (__attribute__((address_space(3))) unsigned int*)((ldsbase) + r8_ * 512), \
                16, 0, 0);                                                         \
        }                                                                          \
    }

__device__ __forceinline__ bf16x8 frag_ld(const unsigned short* lds, int row, int kc) {
    return *(const bf16x8*)(lds + row * 64 + (((kc) ^ (row & 7)) << 3));
}

// ---------------- fused fp32 -> bf16 conversion (x, Wq, Wk, Wv in one grid) ----------------
__global__ __launch_bounds__(256) void conv_all(
    const float* __restrict__ x, const float* __restrict__ wq,
    const float* __restrict__ wk, const float* __restrict__ wv,
    unsigned short* __restrict__ xb, unsigned short* __restrict__ wqb,
    unsigned short* __restrict__ wkb, unsigned short* __restrict__ wvb) {
    int i = blockIdx.x * 256 + threadIdx.x;
    const float* s; unsigned short* d; int j;
    if (i < NX4)                { s = x;  d = xb;  j = i; }
    else if (i < NX4 + NW4)     { s = wq; d = wqb; j = i - NX4; }
    else if (i < NX4 + 2 * NW4) { s = wk; d = wkb; j = i - NX4 - NW4; }
    else                        { s = wv; d = wvb; j = i - NX4 - 2 * NW4; }
    float4 v = ((const float4*)s)[j];
    ushort4 o;
    o.x = f2bf(v.x); o.y = f2bf(v.y); o.z = f2bf(v.z); o.w = f2bf(v.w);
    ((ushort4*)d)[j] = o;
}

// ---------------- per-point attr table: 3D unit vector + log2-scaled time ----------------
// {x, y, z, t*log2e}; masked points get t-sentinel 1e9 -> score ~ -1.4e9 -> exp2 -> 0.
__global__ __launch_bounds__(256) void trig_prep(const float* __restrict__ lat,
                                                 const float* __restrict__ lon,
                                                 const float* __restrict__ tm,
                                                 const int* __restrict__ mask,
                                                 float* __restrict__ trigp) {
    int i = blockIdx.x * blockDim.x + threadIdx.x;
    if (i < BS_TOT) {
        const float RAD = 0.017453292519943295f;
        const float LOG2E = 1.442695041f;
        float la = lat[i] * RAD, lo = lon[i] * RAD;
        float cla = cosf(la);
        float4 o = {cla * cosf(lo), cla * sinf(lo), sinf(la),
                    mask[i] ? tm[i] * LOG2E : 1e9f};
        ((float4*)trigp)[i] = o;
    }
}

// ---------------- QKV projection GEMM: one 128x128 tile of one output ----------------
// grid (BS_TOT/128, 12): y -> (o = y>>2, n0 = (y&3)*128)
// o==2 (V): epilogue transposes the tile through LDS so the V^T store is
// 16B/lane, 256B-contiguous per 16 lanes. LDS reused: Ts aliases As|Bs.
// launch_bounds (256,4): 4 blocks/CU co-resident to hide barrier drains.
__global__ __launch_bounds__(256, 4) void qkv_gemm(
    const unsigned short* __restrict__ xb,
    const unsigned short* __restrict__ Wqb, const unsigned short* __restrict__ Wkb,
    const unsigned short* __restrict__ Wvb,
    const float* __restrict__ bq, const float* __restrict__ bk, const float* __restrict__ bv,
    unsigned short* __restrict__ Qb, unsigned short* __restrict__ Kb,
    unsigned short* __restrict__ VTb) {
    __shared__ __align__(16) unsigned short smem[128 * 128];   // 32 KB
    unsigned short* const As = smem;               // [128*64]
    unsigned short* const Bs = smem + 128 * 64;    // [128*64]

    const int tid = threadIdx.x, lane = tid & 63, wave = tid >> 6;
    const int lq = lane & 15, quad = lane >> 4;
    const int w0 = wave & 1, w1 = wave >> 1;
    const int m0 = blockIdx.x * 128;
    const int o = blockIdx.y >> 2, n0 = (blockIdx.y & 3) * 128;
    const unsigned short* W = (o == 0) ? Wqb : (o == 1) ? Wkb : Wvb;
    const float* bias = (o == 0) ? bq : (o == 1) ? bk : bv;

    f32x4 acc[4][4];
    #pragma unroll
    for (int mi = 0; mi < 4; ++mi)
        #pragma unroll
        for (int ni = 0; ni < 4; ++ni) acc[mi][ni] = (f32x4){0.f, 0.f, 0.f, 0.f};

    const unsigned short* Ag = xb + (size_t)m0 * DIM;
    const unsigned short* Bg = W + (size_t)n0 * DIM;

    for (int kc = 0; kc < 8; ++kc) {
        __syncthreads();
        STAGE64(Ag + kc * 64, DIM, As, 128);
        STAGE64(Bg + kc * 64, DIM, Bs, 128);
        __syncthreads();
        #pragma unroll
        for (int ks = 0; ks < 2; ++ks) {
            bf16x8 af[4], bfr[4];
            #pragma unroll
            for (int mi = 0; mi < 4; ++mi) af[mi] = frag_ld(As, w0 * 64 + mi * 16 + lq, ks * 4 + quad);
            #pragma unroll
            for (int ni = 0; ni < 4; ++ni) bfr[ni] = frag_ld(Bs, w1 * 64 + ni * 16 + lq, ks * 4 + quad);
            #pragma unroll
            for (int mi = 0; mi < 4; ++mi)
                #pragma unroll
                for (int ni = 0; ni < 4; ++ni)
                    acc[mi][ni] = mfma16(af[mi], bfr[ni], acc[mi][ni]);
        }
    }

    if (o < 2) {
        unsigned short* G = (o == 0) ? Qb : Kb;
        #pragma unroll
        for (int ni = 0; ni < 4; ++ni) {
            int e = n0 + w1 * 64 + ni * 16 + lq;
            float be = bias[e];
            #pragma unroll
            for (int mi = 0; mi < 4; ++mi)
                #pragma unroll
                for (int r = 0; r < 4; ++r) {
                    int mrow = m0 + w0 * 64 + mi * 16 + quad * 4 + r;
                    G[(size_t)mrow * DIM + e] = f2bf(acc[mi][ni][r] + be);
                }
        }
    } else {
        // ---- V: transpose through LDS, coalesced V^T store ----
        __syncthreads();   // all waves done reading As/Bs
        #pragma unroll
        for (int ni = 0; ni < 4; ++ni) {
            int e = w1 * 64 + ni * 16 + lq;
            float be = bias[n0 + e];
            #pragma unroll
            for (int mi = 0; mi < 4; ++mi) {
                int s = w0 * 64 + mi * 16 + quad * 4;
                ushort4 pk;
                pk.x = f2bf(acc[mi][ni][0] + be);
                pk.y = f2bf(acc[mi][ni][1] + be);
                pk.z = f2bf(acc[mi][ni][2] + be);
                pk.w = f2bf(acc[mi][ni][3] + be);
                int addr = (e * 256 + s * 2) ^ ((e & 7) << 4);
                *(ushort4*)((char*)smem + addr) = pk;
            }
        }
        __syncthreads();
        const int bb = m0 >> 11, sbase = m0 & 2047;
        #pragma unroll
        for (int p = 0; p < 8; ++p) {
            int e = p * 16 + (tid >> 4);
            int s0 = (tid & 15) * 8;
            int addr = (e * 256 + s0 * 2) ^ ((e & 7) << 4);
            u16x8 v = *(const u16x8*)((const char*)smem + addr);
            *(u16x8*)&VTb[((size_t)bb * DIM + n0 + e) * SEQ + sbase + s0] = v;
        }
    }
}

// ---------------- phase 1: 128x128 score tile, NO-SHIFT softmax (round-8 proven) ----------------
// log2-domain scores: s2 = qk*scale*log2e - 2R*log2e*asin(u) - |dt|*log2e.
// P = exp2(s2) directly (no max shift; diagonal bounds the row sum). Far pairs
// (d > ~100 km) naturally underflow to exactly 0.0 -> zero P entries and zero
// Lc chunks, which rowinv/pv exploit. Math-paced dense P stores (the proven
// memory-friendly pattern; screens/LDS-flush variants all regressed).
// grid: 1D 2048, b = id&7 -> one batch per XCD.
__global__ __launch_bounds__(256, 3) void score_kernel(
    const unsigned short* __restrict__ Qb, const unsigned short* __restrict__ Kb,
    const float* __restrict__ trigp, unsigned short* __restrict__ Pbuf,
    float* __restrict__ Lc) {
    __shared__ __align__(16) unsigned short As[128 * 64];
    __shared__ __align__(16) unsigned short Bs[128 * 64];

    const int tid = threadIdx.x, lane = tid & 63, wave = tid >> 6;
    const int lq = lane & 15, quad = lane >> 4;
    const int w0 = wave & 1, w1 = wave >> 1;
    const int id = blockIdx.x;
    const int b = id & 7, t = id >> 3;
    const int it = t & 15, jt = t >> 4;
    const int i0 = it * 128, j0 = jt * 128;
    const size_t rowQ = (size_t)b * SEQ + i0;
    const size_t rowK = (size_t)b * SEQ + j0;

    f32x4 acc[4][4];
    #pragma unroll
    for (int mi = 0; mi < 4; ++mi)
        #pragma unroll
        for (int ni = 0; ni < 4; ++ni) acc[mi][ni] = (f32x4){0.f, 0.f, 0.f, 0.f};

    const unsigned short* Ag = Qb + rowQ * DIM;
    const unsigned short* Bg = Kb + rowK * DIM;

    for (int kc = 0; kc < 8; ++kc) {
        __syncthreads();
        STAGE64(Ag + kc * 64, DIM, As, 128);
        STAGE64(Bg + kc * 64, DIM, Bs, 128);
        __syncthreads();
        #pragma unroll
        for (int ks = 0; ks < 2; ++ks) {
            bf16x8 af[4], bfr[4];
            #pragma unroll
            for (int mi = 0; mi < 4; ++mi) af[mi] = frag_ld(As, w0 * 64 + mi * 16 + lq, ks * 4 + quad);
            #pragma unroll
            for (int ni = 0; ni < 4; ++ni) bfr[ni] = frag_ld(Bs, w1 * 64 + ni * 16 + lq, ks * 4 + quad);
            #pragma unroll
            for (int mi = 0; mi < 4; ++mi)
                #pragma unroll
                for (int ni = 0; ni < 4; ++ni)
                    acc[mi][ni] = mfma16(af[mi], bfr[ni], acc[mi][ni]);
        }
    }

    // ---- constants (all folded with log2e) ----
    const float SC2 = 0.04419417382415922f * 1.442695041f;   // (1/sqrt(512))*log2e
    const float KQ = 12742.0f * 1.442695041f;                // 2R*log2e
    const float KHPI = 12742.0f * 1.442695041f * 1.5707963268f;
    // A&S 4.4.47: asin(u) = pi/2 - sqrt(1-u)*P(u), |eps| <= 2e-8
    const float A0 = 1.5707963050f, A1 = -0.2145988016f, A2 = 0.0889789874f,
                A3 = -0.0501743046f, A4 = 0.0308918810f, A5 = -0.0170881256f,
                A6 = 0.0066700901f, A7 = -0.0012624911f;

    // ---- fused sweep: bias -> exp2 -> partial row sum -> store P ----
    float sm[16];
    #pragma unroll
    for (int i = 0; i < 16; ++i) sm[i] = 0.f;

    // hoist the 4 K-attr loads (reused across all mi)
    float4 ka[4];
    #pragma unroll
    for (int ni = 0; ni < 4; ++ni)
        ka[ni] = ((const float4*)trigp)[rowK + w1 * 64 + ni * 16 + lq];

    #pragma unroll
    for (int mi = 0; mi < 4; ++mi) {
        float4 qa[4];
        #pragma unroll
        for (int r = 0; r < 4; ++r)
            qa[r] = ((const float4*)trigp)[rowQ + w0 * 64 + mi * 16 + quad * 4 + r];
        #pragma unroll
        for (int ni = 0; ni < 4; ++ni) {
            float4 k = ka[ni];
            #pragma unroll
            for (int r = 0; r < 4; ++r) {
                float dx = qa[r].x - k.x;
                float dy = qa[r].y - k.y;
                float dz = qa[r].z - k.z;
                float ch2 = fmaf(dx, dx, fmaf(dy, dy, dz * dz));   // chord^2
                float u = fminf(0.5f * __builtin_amdgcn_sqrtf(ch2), 1.0f);
                float vv = __builtin_amdgcn_sqrtf(1.0f - u);
                float pl = fmaf(A7, u, A6);
                pl = fmaf(pl, u, A5); pl = fmaf(pl, u, A4); pl = fmaf(pl, u, A3);
                pl = fmaf(pl, u, A2); pl = fmaf(pl, u, A1); pl = fmaf(pl, u, A0);
                float sv = fmaf(acc[mi][ni][r], SC2, -KHPI);       // qk - 2R*(pi/2)
                sv = fmaf(vv * pl, KQ, sv);                        // + 2R*sqrt(1-u)*P(u)
                sv -= fabsf(k.w - qa[r].w);                        // - |dt| (log2-scaled)
                float p = __builtin_amdgcn_exp2f(sv);
                sm[mi * 4 + r] += p;
                Pbuf[(rowQ + w0 * 64 + mi * 16 + quad * 4 + r) * SEQ + j0 + w1 * 64 +
                     ni * 16 + lq] = f2bf(p);
            }
        }
    }
    #pragma unroll
    for (int o = 1; o < 16; o <<= 1)
        #pragma unroll
        for (int i = 0; i < 16; ++i) sm[i] += __shfl_xor(sm[i], o);

    if (lq == 0) {
        int chunk = jt * 2 + w1;
        #pragma unroll
        for (int mi = 0; mi < 4; ++mi)
            #pragma unroll
            for (int r = 0; r < 4; ++r) {
                size_t g = rowQ + w0 * 64 + mi * 16 + quad * 4 + r;
                Lc[g * 32 + chunk] = sm[mi * 4 + r];
            }
    }
}

// ---------------- phase 1.5: per-row 1/L + nonzero-chunk bitmask ----------------
// Lc chunk == 0.0 iff all 64 p in that chunk underflowed to 0 (far pairs) —
// natural sparsity, no screen needed.
__global__ __launch_bounds__(256) void rowinv(
    const float* __restrict__ Lc, float* __restrict__ Srow,
    unsigned int* __restrict__ rowmask) {
    int g = blockIdx.x * 256 + threadIdx.x;
    if (g >= BS_TOT) return;
    float L = 0.f;
    unsigned int m = 0;
    #pragma unroll
    for (int c = 0; c < 32; ++c) {
        float v = Lc[(size_t)g * 32 + c];
        L += v;
        if (v != 0.0f) m |= (1u << c);
    }
    Srow[g] = 1.0f / L;
    rowmask[g] = m;
}

// ---------------- phase 2: O = Srow * (P V) with zero-chunk skipping ----------------
// 128x64 tile, 1024 blocks = 4/CU. Per block: OR the 128 row masks -> skip
// staging+MFMA for 64-key chunks whose P columns are entirely zero (exact:
// dropped terms contribute +0.0). ~50% of chunks skip at block granularity.
// grid: 1D 1024, b = id&7 -> batch-per-XCD.
__global__ __launch_bounds__(256, 4) void pv_kernel(
    const unsigned short* __restrict__ Pbuf, const unsigned short* __restrict__ VTb,
    const float* __restrict__ Srow, const unsigned int* __restrict__ rowmask,
    float* __restrict__ Out) {
    __shared__ __align__(16) unsigned short As[128 * 64];
    __shared__ __align__(16) unsigned short Bs[64 * 64];
    __shared__ unsigned int msk[128];

    const int tid = threadIdx.x, lane = tid & 63, wave = tid >> 6;
    const int lq = lane & 15, quad = lane >> 4;
    const int id = blockIdx.x;
    const int b = id & 7, t = id >> 3;
    const int d0 = (t & 7) * 64, i0 = (t >> 3) * 128;

    if (tid < 128) msk[tid] = rowmask[(size_t)b * SEQ + i0 + tid];
    __syncthreads();
    if (tid < 64) msk[tid] |= msk[tid + 64];
    __syncthreads();
    if (tid < 32) msk[tid] |= msk[tid + 32];
    __syncthreads();
    if (tid < 16) msk[tid] |= msk[tid + 16];
    __syncthreads();
    if (tid < 8) msk[tid] |= msk[tid + 8];
    __syncthreads();
    if (tid < 4) msk[tid] |= msk[tid + 4];
    __syncthreads();
    if (tid < 2) msk[tid] |= msk[tid + 2];
    __syncthreads();
    if (tid == 0) msk[0] |= msk[1];
    __syncthreads();
    const unsigned int cmask = msk[0];

    f32x4 acc[2][4];
    #pragma unroll
    for (int mi = 0; mi < 2; ++mi)
        #pragma unroll
        for (int ni = 0; ni < 4; ++ni) acc[mi][ni] = (f32x4){0.f, 0.f, 0.f, 0.f};

    const unsigned short* Ag = Pbuf + ((size_t)b * SEQ + i0) * SEQ;
    const unsigned short* Bg = VTb + ((size_t)b * DIM + d0) * SEQ;

    #pragma unroll 1
    for (int kc = 0; kc < 32; ++kc) {
        if (!((cmask >> kc) & 1u)) continue;   // whole 64-key chunk is zero P
        __syncthreads();
        STAGE64(Ag + kc * 64, SEQ, As, 128);
        STAGE64(Bg + kc * 64, SEQ, Bs, 64);
        __syncthreads();
        #pragma unroll
        for (int ks = 0; ks < 2; ++ks) {
            bf16x8 af[2], bfr[4];
            #pragma unroll
            for (int mi = 0; mi < 2; ++mi) af[mi] = frag_ld(As, wave * 32 + mi * 16 + lq, ks * 4 + quad);
            #pragma unroll
            for (int ni = 0; ni < 4; ++ni) bfr[ni] = frag_ld(Bs, ni * 16 + lq, ks * 4 + quad);
            #pragma unroll
            for (int mi = 0; mi < 2; ++mi)
                #pragma unroll
                for (int ni = 0; ni < 4; ++ni)
                    acc[mi][ni] = mfma16(af[mi], bfr[ni], acc[mi][ni]);
        }
    }

    #pragma unroll
    for (int mi = 0; mi < 2; ++mi)
        #pragma unroll
        for (int r = 0; r < 4; ++r) {
            size_t grow = (size_t)b * SEQ + i0 + wave * 32 + mi * 16 + quad * 4 + r;
            float s = Srow[grow];
            size_t orow = grow * DIM;
            #pragma unroll
            for (int ni = 0; ni < 4; ++ni)
                Out[orow + d0 + ni * 16 + lq] = acc[mi][ni][r] * s;
        }
}

extern "C" void kernel_launch(void* const* d_in, const int* in_sizes, int n_in,
                              void* d_out, int out_size, void* d_ws, size_t ws_size,
                              hipStream_t stream) {
    (void)in_sizes; (void)n_in; (void)out_size; (void)ws_size;
    const float* x    = (const float*)d_in[0];
    const float* tseq = (const float*)d_in[1];
    const float* lat  = (const float*)d_in[2];
    const float* lon  = (const float*)d_in[3];
    const int*   mk   = (const int*)d_in[4];
    const float* Wq   = (const float*)d_in[5];
    const float* bq   = (const float*)d_in[6];
    const float* Wk   = (const float*)d_in[7];
    const float* bk   = (const float*)d_in[8];
    const float* Wv   = (const float*)d_in[9];
    const float* bv   = (const float*)d_in[10];
    float* out = (float*)d_out;

    unsigned short* xb  = (unsigned short*)d_ws;
    unsigned short* Qb  = xb + (size_t)BS_TOT * DIM;
    unsigned short* Kb  = Qb + (size_t)BS_TOT * DIM;
    unsigned short* VTb = Kb + (size_t)BS_TOT * DIM;
    unsigned short* Wqb = VTb + (size_t)BS_TOT * DIM;
    unsigned short* Wkb = Wqb + DIM * DIM;
    unsigned short* Wvb = Wkb + DIM * DIM;
    float* trigp = (float*)(Wvb + DIM * DIM);                  // 16384 x 4 f32
    unsigned short* Pbuf = (unsigned short*)(trigp + (size_t)BS_TOT * 4);  // 67 MB
    float* Lc = (float*)(Pbuf + (size_t)BS_TOT * SEQ);         // 16384 x 32
    float* Srow = Lc + (size_t)BS_TOT * 32;                    // 16384
    unsigned int* rowmask = (unsigned int*)(Srow + BS_TOT);    // 16384

    conv_all<<<(NX4 + 3 * NW4) / 256, 256, 0, stream>>>(
        x, Wq, Wk, Wv, xb, Wqb, Wkb, Wvb);
    trig_prep<<<(BS_TOT + 255) / 256, 256, 0, stream>>>(lat, lon, tseq, mk, trigp);

    qkv_gemm<<<dim3(BS_TOT / 128, 12), 256, 0, stream>>>(
        xb, Wqb, Wkb, Wvb, bq, bk, bv, Qb, Kb, VTb);

    score_kernel<<<dim3((SEQ / 128) * (SEQ / 128) * BSZ), 256, 0, stream>>>(
        Qb, Kb, trigp, Pbuf, Lc);
    rowinv<<<(BS_TOT + 255) / 256, 256, 0, stream>>>(Lc, Srow, rowmask);
    pv_kernel<<<dim3((SEQ / 128) * (DIM / 64) * BSZ), 256, 0, stream>>>(
        Pbuf, VTb, Srow, rowmask, out);
}